// Round 2
// baseline (390.010 us; speedup 1.0000x reference)
//
#include <hip/hip_runtime.h>

// EmbeddingFusionLayer: out_users[n,e]    = sum_v softmax(uw)[v] * view_users[v,n,e]
//                       out_products[m,e] = sum_v softmax(pw)[v] * view_products[v,m,e]
// HBM-BW-bound. Round 2: branch-free uniform loops (compile-time trip counts),
// unroll-2 for 8 in-flight loads/wave, non-temporal hints (single-pass data).

typedef float f4 __attribute__((ext_vector_type(4)));  // trivially copyable, builtin-compatible

constexpr long long N_USER = 1000000LL;
constexpr long long N_PRODUCT = 500000LL;
constexpr int EMB = 64;

constexpr int BLOCK = 256;
constexpr int GRID = 2048;                       // 2048 blocks * 4 waves = 8192 waves = 32/CU
constexpr int STRIDE = BLOCK * GRID;             // 524288 threads
constexpr int NU4 = (int)(N_USER * EMB / 4);     // 16,000,000 float4 per user view
constexpr int NP4 = (int)(N_PRODUCT * EMB / 4);  //  8,000,000 float4 per product view
constexpr int U_ITERS = NU4 / STRIDE;            // 30
constexpr int U_REM = NU4 % STRIDE;              // 271,360
constexpr int P_ITERS = NP4 / STRIDE;            // 15
constexpr int P_REM = NP4 % STRIDE;              // 135,680

__global__ __launch_bounds__(BLOCK) void fused_view_sum(
    const float* __restrict__ vu,
    const float* __restrict__ vp,
    const float* __restrict__ uwp,
    const float* __restrict__ pwp,
    float* __restrict__ out)
{
    // ---- softmax of the two 4-element weight vectors, per-thread (uniform, cheap)
    float u0 = uwp[0], u1 = uwp[1], u2 = uwp[2], u3 = uwp[3];
    float um = fmaxf(fmaxf(u0, u1), fmaxf(u2, u3));
    float ue0 = expf(u0 - um), ue1 = expf(u1 - um), ue2 = expf(u2 - um), ue3 = expf(u3 - um);
    float uinv = 1.0f / (ue0 + ue1 + ue2 + ue3);
    const float w0 = ue0 * uinv, w1 = ue1 * uinv, w2 = ue2 * uinv, w3 = ue3 * uinv;

    float p0 = pwp[0], p1 = pwp[1], p2 = pwp[2], p3 = pwp[3];
    float pm = fmaxf(fmaxf(p0, p1), fmaxf(p2, p3));
    float pe0 = expf(p0 - pm), pe1 = expf(p1 - pm), pe2 = expf(p2 - pm), pe3 = expf(p3 - pm);
    float pinv = 1.0f / (pe0 + pe1 + pe2 + pe3);
    const float q0 = pe0 * pinv, q1 = pe1 * pinv, q2 = pe2 * pinv, q3 = pe3 * pinv;

    const int tid = blockIdx.x * BLOCK + threadIdx.x;

    const f4* __restrict__ vu4 = (const f4*)vu;
    const f4* __restrict__ vp4 = (const f4*)vp;
    f4* __restrict__ ou4 = (f4*)out;
    f4* __restrict__ op4 = (f4*)(out + N_USER * EMB);

    // ---- users: 30 uniform iterations + 1 conditional tail
#pragma unroll 2
    for (int k = 0; k < U_ITERS; ++k) {
        const int i = tid + k * STRIDE;
        f4 a = __builtin_nontemporal_load(vu4 + i);
        f4 b = __builtin_nontemporal_load(vu4 + i + NU4);
        f4 c = __builtin_nontemporal_load(vu4 + i + 2 * NU4);
        f4 d = __builtin_nontemporal_load(vu4 + i + 3 * NU4);
        f4 r = w0 * a + w1 * b + w2 * c + w3 * d;
        __builtin_nontemporal_store(r, ou4 + i);
    }
    if (tid < U_REM) {
        const int i = tid + U_ITERS * STRIDE;
        f4 a = __builtin_nontemporal_load(vu4 + i);
        f4 b = __builtin_nontemporal_load(vu4 + i + NU4);
        f4 c = __builtin_nontemporal_load(vu4 + i + 2 * NU4);
        f4 d = __builtin_nontemporal_load(vu4 + i + 3 * NU4);
        f4 r = w0 * a + w1 * b + w2 * c + w3 * d;
        __builtin_nontemporal_store(r, ou4 + i);
    }

    // ---- products: 15 uniform iterations + 1 conditional tail
#pragma unroll 2
    for (int k = 0; k < P_ITERS; ++k) {
        const int j = tid + k * STRIDE;
        f4 a = __builtin_nontemporal_load(vp4 + j);
        f4 b = __builtin_nontemporal_load(vp4 + j + NP4);
        f4 c = __builtin_nontemporal_load(vp4 + j + 2 * NP4);
        f4 d = __builtin_nontemporal_load(vp4 + j + 3 * NP4);
        f4 r = q0 * a + q1 * b + q2 * c + q3 * d;
        __builtin_nontemporal_store(r, op4 + j);
    }
    if (tid < P_REM) {
        const int j = tid + P_ITERS * STRIDE;
        f4 a = __builtin_nontemporal_load(vp4 + j);
        f4 b = __builtin_nontemporal_load(vp4 + j + NP4);
        f4 c = __builtin_nontemporal_load(vp4 + j + 2 * NP4);
        f4 d = __builtin_nontemporal_load(vp4 + j + 3 * NP4);
        f4 r = q0 * a + q1 * b + q2 * c + q3 * d;
        __builtin_nontemporal_store(r, op4 + j);
    }
}

extern "C" void kernel_launch(void* const* d_in, const int* in_sizes, int n_in,
                              void* d_out, int out_size, void* d_ws, size_t ws_size,
                              hipStream_t stream) {
    const float* vu = (const float*)d_in[0];   // [4, 1e6, 64]
    const float* vp = (const float*)d_in[1];   // [4, 5e5, 64]
    const float* uw = (const float*)d_in[2];   // [1, 4]
    const float* pw = (const float*)d_in[3];   // [1, 4]
    float* out = (float*)d_out;                // [1e6*64 + 5e5*64] concat

    fused_view_sum<<<GRID, BLOCK, 0, stream>>>(vu, vp, uw, pw, out);
}

// Round 3
// 368.509 us; speedup vs baseline: 1.0583x; 1.0583x over previous
//
#include <hip/hip_runtime.h>

// EmbeddingFusionLayer: out_users[n,e]    = sum_v softmax(uw)[v] * view_users[v,n,e]
//                       out_products[m,e] = sum_v softmax(pw)[v] * view_products[v,m,e]
// HBM-BW-bound. Round 3: per-wave 8KB-per-stream bursts (view-phase-major,
// 8 x dwordx4 back-to-back per stream) to improve DRAM row locality for the
// 5-stream mix. Exact group tiling, no tails; static reg indexing.

typedef float f4 __attribute__((ext_vector_type(4)));

constexpr long long N_USER = 1000000LL;
constexpr long long N_PRODUCT = 500000LL;
constexpr int EMB = 64;

constexpr int BLOCK = 256;
constexpr int GRID = 2048;
constexpr int NWAVES = GRID * (BLOCK / 64);   // 8192 waves
constexpr int JPT = 8;                        // positions (f4) per thread per group
constexpr int GSIZE = 64 * JPT;               // 512 f4 = 8 KB per wave per stream
constexpr int NU4 = (int)(N_USER * EMB / 4);  // 16,000,000  (= 31250 * GSIZE exactly)
constexpr int NP4 = (int)(N_PRODUCT * EMB / 4); // 8,000,000 (= 15625 * GSIZE exactly)
constexpr int UG = NU4 / GSIZE;               // 31250 user groups
constexpr int PG = NP4 / GSIZE;               // 15625 product groups
constexpr int TG = UG + PG;                   // 46875 total groups

__global__ __launch_bounds__(BLOCK) void fused_view_sum(
    const float* __restrict__ vu,
    const float* __restrict__ vp,
    const float* __restrict__ uwp,
    const float* __restrict__ pwp,
    float* __restrict__ out)
{
    // ---- softmax of the two 4-element weight vectors, per-thread (uniform, cheap)
    float u0 = uwp[0], u1 = uwp[1], u2 = uwp[2], u3 = uwp[3];
    float um = fmaxf(fmaxf(u0, u1), fmaxf(u2, u3));
    float ue0 = expf(u0 - um), ue1 = expf(u1 - um), ue2 = expf(u2 - um), ue3 = expf(u3 - um);
    float uinv = 1.0f / (ue0 + ue1 + ue2 + ue3);
    const float w0 = ue0 * uinv, w1 = ue1 * uinv, w2 = ue2 * uinv, w3 = ue3 * uinv;

    float p0 = pwp[0], p1 = pwp[1], p2 = pwp[2], p3 = pwp[3];
    float pm = fmaxf(fmaxf(p0, p1), fmaxf(p2, p3));
    float pe0 = expf(p0 - pm), pe1 = expf(p1 - pm), pe2 = expf(p2 - pm), pe3 = expf(p3 - pm);
    float pinv = 1.0f / (pe0 + pe1 + pe2 + pe3);
    const float q0 = pe0 * pinv, q1 = pe1 * pinv, q2 = pe2 * pinv, q3 = pe3 * pinv;

    const int flat = blockIdx.x * BLOCK + threadIdx.x;
    const int wave = flat >> 6;
    const int lane = flat & 63;

    const f4* __restrict__ vu4 = (const f4*)vu;
    const f4* __restrict__ vp4 = (const f4*)vp;
    f4* __restrict__ ou4 = (f4*)out;
    f4* __restrict__ op4 = (f4*)(out + N_USER * EMB);

    // One 8KB-per-stream group per wave per iteration; group id space covers
    // users then products (branch is wave-uniform).
    for (int g = wave; g < TG; g += NWAVES) {
        const bool isU = g < UG;
        const f4* __restrict__ src = isU ? vu4 : vp4;
        f4* __restrict__ dst = isU ? ou4 : op4;
        const int stride = isU ? NU4 : NP4;
        const int base = (isU ? g : g - UG) * GSIZE + lane;
        const float c0 = isU ? w0 : q0;
        const float c1 = isU ? w1 : q1;
        const float c2 = isU ? w2 : q2;
        const float c3 = isU ? w3 : q3;

        f4 acc[JPT];
        f4 t[JPT];

        // view 0: 8 back-to-back 1KB wave loads = 8KB contiguous burst
#pragma unroll
        for (int j = 0; j < JPT; ++j) t[j] = __builtin_nontemporal_load(src + base + j * 64);
#pragma unroll
        for (int j = 0; j < JPT; ++j) acc[j] = c0 * t[j];
        // view 1
#pragma unroll
        for (int j = 0; j < JPT; ++j) t[j] = __builtin_nontemporal_load(src + stride + base + j * 64);
#pragma unroll
        for (int j = 0; j < JPT; ++j) acc[j] += c1 * t[j];
        // view 2
#pragma unroll
        for (int j = 0; j < JPT; ++j) t[j] = __builtin_nontemporal_load(src + 2 * stride + base + j * 64);
#pragma unroll
        for (int j = 0; j < JPT; ++j) acc[j] += c2 * t[j];
        // view 3
#pragma unroll
        for (int j = 0; j < JPT; ++j) t[j] = __builtin_nontemporal_load(src + 3 * stride + base + j * 64);
#pragma unroll
        for (int j = 0; j < JPT; ++j) acc[j] += c3 * t[j];
        // 8KB contiguous store burst (plain stores — match the fast fill path)
#pragma unroll
        for (int j = 0; j < JPT; ++j) dst[base + j * 64] = acc[j];
    }
}

extern "C" void kernel_launch(void* const* d_in, const int* in_sizes, int n_in,
                              void* d_out, int out_size, void* d_ws, size_t ws_size,
                              hipStream_t stream) {
    const float* vu = (const float*)d_in[0];   // [4, 1e6, 64]
    const float* vp = (const float*)d_in[1];   // [4, 5e5, 64]
    const float* uw = (const float*)d_in[2];   // [1, 4]
    const float* pw = (const float*)d_in[3];   // [1, 4]
    float* out = (float*)d_out;                // [1e6*64 + 5e5*64] concat

    fused_view_sum<<<GRID, BLOCK, 0, stream>>>(vu, vp, uw, pw, out);
}

// Round 4
// 364.825 us; speedup vs baseline: 1.0690x; 1.0101x over previous
//
#include <hip/hip_runtime.h>

// EmbeddingFusionLayer: out_users[n,e]    = sum_v softmax(uw)[v] * view_users[v,n,e]
//                       out_products[m,e] = sum_v softmax(pw)[v] * view_products[v,m,e]
// HBM-BW-bound. Round 4: 16KB-per-stream bursts for the user region (JPT=16),
// 8KB for products. Fewer concurrent streams x longer same-row runs.
// Exact tiling (no tails). All register arrays statically indexed.

typedef float f4 __attribute__((ext_vector_type(4)));

constexpr long long N_USER = 1000000LL;
constexpr long long N_PRODUCT = 500000LL;
constexpr int EMB = 64;

constexpr int BLOCK = 256;
constexpr int GRID = 2048;
constexpr int NWAVES = GRID * (BLOCK / 64);      // 8192 waves
constexpr int NU4 = (int)(N_USER * EMB / 4);     // 16,000,000 f4 per user view
constexpr int NP4 = (int)(N_PRODUCT * EMB / 4);  //  8,000,000 f4 per product view

constexpr int JU = 16;                 // user: 16 f4/lane -> 16KB/wave/stream
constexpr int JP = 8;                  // product: 8 f4/lane -> 8KB/wave/stream
constexpr int GU = 64 * JU;            // 1024 f4 per user group
constexpr int GP = 64 * JP;            // 512 f4 per product group
constexpr int UG = NU4 / GU;           // 15625  (exact)
constexpr int PG = NP4 / GP;           // 15625  (exact)
constexpr int TG = UG + PG;            // 31250

__global__ __launch_bounds__(BLOCK) void fused_view_sum(
    const float* __restrict__ vu,
    const float* __restrict__ vp,
    const float* __restrict__ uwp,
    const float* __restrict__ pwp,
    float* __restrict__ out)
{
    // ---- softmax of the two 4-element weight vectors, per-thread (uniform, cheap)
    float u0 = uwp[0], u1 = uwp[1], u2 = uwp[2], u3 = uwp[3];
    float um = fmaxf(fmaxf(u0, u1), fmaxf(u2, u3));
    float ue0 = expf(u0 - um), ue1 = expf(u1 - um), ue2 = expf(u2 - um), ue3 = expf(u3 - um);
    float uinv = 1.0f / (ue0 + ue1 + ue2 + ue3);
    const float w0 = ue0 * uinv, w1 = ue1 * uinv, w2 = ue2 * uinv, w3 = ue3 * uinv;

    float p0 = pwp[0], p1 = pwp[1], p2 = pwp[2], p3 = pwp[3];
    float pm = fmaxf(fmaxf(p0, p1), fmaxf(p2, p3));
    float pe0 = expf(p0 - pm), pe1 = expf(p1 - pm), pe2 = expf(p2 - pm), pe3 = expf(p3 - pm);
    float pinv = 1.0f / (pe0 + pe1 + pe2 + pe3);
    const float q0 = pe0 * pinv, q1 = pe1 * pinv, q2 = pe2 * pinv, q3 = pe3 * pinv;

    const int flat = blockIdx.x * BLOCK + threadIdx.x;
    const int wave = flat >> 6;
    const int lane = flat & 63;

    const f4* __restrict__ vu4 = (const f4*)vu;
    const f4* __restrict__ vp4 = (const f4*)vp;
    f4* __restrict__ ou4 = (f4*)out;
    f4* __restrict__ op4 = (f4*)(out + N_USER * EMB);

    for (int g = wave; g < TG; g += NWAVES) {
        if (g < UG) {
            // -------- users: 16KB contiguous burst per view stream --------
            const int base = g * GU + lane;
            f4 t[JU];
            f4 acc[JU];
            // view 0
#pragma unroll
            for (int j = 0; j < JU; ++j) t[j] = __builtin_nontemporal_load(vu4 + base + j * 64);
#pragma unroll
            for (int j = 0; j < JU; ++j) acc[j] = w0 * t[j];
            // view 1
#pragma unroll
            for (int j = 0; j < JU; ++j) t[j] = __builtin_nontemporal_load(vu4 + NU4 + base + j * 64);
#pragma unroll
            for (int j = 0; j < JU; ++j) acc[j] += w1 * t[j];
            // view 2
#pragma unroll
            for (int j = 0; j < JU; ++j) t[j] = __builtin_nontemporal_load(vu4 + 2 * NU4 + base + j * 64);
#pragma unroll
            for (int j = 0; j < JU; ++j) acc[j] += w2 * t[j];
            // view 3
#pragma unroll
            for (int j = 0; j < JU; ++j) t[j] = __builtin_nontemporal_load(vu4 + 3 * NU4 + base + j * 64);
#pragma unroll
            for (int j = 0; j < JU; ++j) acc[j] += w3 * t[j];
            // 16KB contiguous store burst
#pragma unroll
            for (int j = 0; j < JU; ++j) ou4[base + j * 64] = acc[j];
        } else {
            // -------- products: 8KB contiguous burst per view stream --------
            const int base = (g - UG) * GP + lane;
            f4 t[JP];
            f4 acc[JP];
            // view 0
#pragma unroll
            for (int j = 0; j < JP; ++j) t[j] = __builtin_nontemporal_load(vp4 + base + j * 64);
#pragma unroll
            for (int j = 0; j < JP; ++j) acc[j] = q0 * t[j];
            // view 1
#pragma unroll
            for (int j = 0; j < JP; ++j) t[j] = __builtin_nontemporal_load(vp4 + NP4 + base + j * 64);
#pragma unroll
            for (int j = 0; j < JP; ++j) acc[j] += q1 * t[j];
            // view 2
#pragma unroll
            for (int j = 0; j < JP; ++j) t[j] = __builtin_nontemporal_load(vp4 + 2 * NP4 + base + j * 64);
#pragma unroll
            for (int j = 0; j < JP; ++j) acc[j] += q2 * t[j];
            // view 3
#pragma unroll
            for (int j = 0; j < JP; ++j) t[j] = __builtin_nontemporal_load(vp4 + 3 * NP4 + base + j * 64);
#pragma unroll
            for (int j = 0; j < JP; ++j) acc[j] += q3 * t[j];
            // 8KB contiguous store burst
#pragma unroll
            for (int j = 0; j < JP; ++j) op4[base + j * 64] = acc[j];
        }
    }
}

extern "C" void kernel_launch(void* const* d_in, const int* in_sizes, int n_in,
                              void* d_out, int out_size, void* d_ws, size_t ws_size,
                              hipStream_t stream) {
    const float* vu = (const float*)d_in[0];   // [4, 1e6, 64]
    const float* vp = (const float*)d_in[1];   // [4, 5e5, 64]
    const float* uw = (const float*)d_in[2];   // [1, 4]
    const float* pw = (const float*)d_in[3];   // [1, 4]
    float* out = (float*)d_out;                // [1e6*64 + 5e5*64] concat

    fused_view_sum<<<GRID, BLOCK, 0, stream>>>(vu, vp, uw, pw, out);
}